// Round 1
// baseline (148.729 us; speedup 1.0000x reference)
//
#include <hip/hip_runtime.h>
#include <math.h>

#define BLOCK 256

__device__ __forceinline__ void combine_md(float& m, float& d, float m2, float d2) {
    float nm = fmaxf(m, m2);
    d = d * __expf(m - nm) + d2 * __expf(m2 - nm);
    m = nm;
}

// One block per row: online (max, sum-exp) + running sum over the row,
// then per-row smoothed-label KL term written to row_loss[row].
__global__ __launch_bounds__(BLOCK) void ls_row_kernel(
    const float* __restrict__ logits, const int* __restrict__ target,
    float* __restrict__ row_loss, int V,
    float conf, float smooth, float log_c, float log_s)
{
    const int row = blockIdx.x;
    const int tid = threadIdx.x;
    const float4* rp = reinterpret_cast<const float4*>(logits + (size_t)row * V);
    const int n4 = V >> 2;  // V divisible by 4 (49408)

    // 4 independent online-softmax accumulator chains for ILP
    float m0 = -3.0e38f, m1 = -3.0e38f, m2 = -3.0e38f, m3 = -3.0e38f;
    float d0 = 0.f, d1 = 0.f, d2 = 0.f, d3 = 0.f;
    float s  = 0.f;

    for (int i = tid; i < n4; i += BLOCK) {
        float4 v = rp[i];
        s += (v.x + v.y) + (v.z + v.w);
        // rare-branch online update: exactly one exp on the common path
        if (v.x > m0) { d0 = d0 * __expf(m0 - v.x) + 1.f; m0 = v.x; } else { d0 += __expf(v.x - m0); }
        if (v.y > m1) { d1 = d1 * __expf(m1 - v.y) + 1.f; m1 = v.y; } else { d1 += __expf(v.y - m1); }
        if (v.z > m2) { d2 = d2 * __expf(m2 - v.z) + 1.f; m2 = v.z; } else { d2 += __expf(v.z - m2); }
        if (v.w > m3) { d3 = d3 * __expf(m3 - v.w) + 1.f; m3 = v.w; } else { d3 += __expf(v.w - m3); }
    }
    combine_md(m0, d0, m1, d1);
    combine_md(m2, d2, m3, d3);
    combine_md(m0, d0, m2, d2);

    // 64-lane butterfly reduce (wave = 64 on CDNA)
    #pragma unroll
    for (int off = 32; off; off >>= 1) {
        float mm = __shfl_xor(m0, off);
        float dd = __shfl_xor(d0, off);
        s += __shfl_xor(s, off);
        combine_md(m0, d0, mm, dd);
    }

    __shared__ float sm[BLOCK / 64], sd[BLOCK / 64], ss[BLOCK / 64];
    const int lane = tid & 63, wv = tid >> 6;
    if (lane == 0) { sm[wv] = m0; sd[wv] = d0; ss[wv] = s; }
    __syncthreads();

    if (tid == 0) {
        float M = sm[0], D = sd[0], S = ss[0];
        #pragma unroll
        for (int w = 1; w < BLOCK / 64; ++w) {
            combine_md(M, D, sm[w], sd[w]);
            S += ss[w];
        }
        const int t = target[row];
        const float xt  = logits[(size_t)row * V + t];
        const float lse = M + logf(D);
        const float lq_t   = xt - lse;
        const float sum_lq = S - (float)V * lse;
        const float per = conf * (log_c - lq_t)
                        + smooth * ((float)(V - 1) * log_s - (sum_lq - lq_t));
        row_loss[row] = (t != 0) ? per : 0.f;  // IGNORE_INDEX = 0
    }
}

// Deterministic single-block tree sum of the per-row losses.
__global__ __launch_bounds__(256) void ls_sum_kernel(
    const float* __restrict__ row_loss, float* __restrict__ out, int n)
{
    float s = 0.f;
    for (int i = threadIdx.x; i < n; i += 256) s += row_loss[i];
    #pragma unroll
    for (int off = 32; off; off >>= 1) s += __shfl_xor(s, off);
    __shared__ float ss[4];
    if ((threadIdx.x & 63) == 0) ss[threadIdx.x >> 6] = s;
    __syncthreads();
    if (threadIdx.x == 0) out[0] = (ss[0] + ss[1]) + (ss[2] + ss[3]);
}

extern "C" void kernel_launch(void* const* d_in, const int* in_sizes, int n_in,
                              void* d_out, int out_size, void* d_ws, size_t ws_size,
                              hipStream_t stream)
{
    const float* logits = (const float*)d_in[0];
    const int*   target = (const int*)d_in[1];
    const int rows = in_sizes[1];
    const int V    = in_sizes[0] / rows;

    float* row_loss = (float*)d_ws;  // rows * 4 bytes

    const double conf   = 0.7;                    // 1 - LABEL_SMOOTHING
    const double smooth = 0.3 / (double)(V - 1);  // SMOOTH_VAL

    ls_row_kernel<<<rows, BLOCK, 0, stream>>>(
        logits, target, row_loss, V,
        (float)conf, (float)smooth, (float)log(conf), (float)log(smooth));
    ls_sum_kernel<<<1, 256, 0, stream>>>(row_loss, (float*)d_out, rows);
}